// Round 4
// baseline (1262.735 us; speedup 1.0000x reference)
//
#include <hip/hip_runtime.h>

constexpr int H = 128;   // hidden width (all layer outputs)

typedef __attribute__((ext_vector_type(8))) __bf16 bf16x8;
typedef __attribute__((ext_vector_type(4))) float  f32x4;

__device__ __forceinline__ unsigned short f2bf(float f) {
  unsigned u = __builtin_bit_cast(unsigned, f);
  u += 0x7FFFu + ((u >> 16) & 1u);          // RNE
  return (unsigned short)(u >> 16);
}
__device__ __forceinline__ float bf2f(unsigned short b) {
  unsigned u = ((unsigned)b) << 16;
  return __builtin_bit_cast(float, u);
}

// ---------------- fp32 -> bf16 elementwise convert --------------------------
__global__ __launch_bounds__(256) void conv_bf_k(const float* __restrict__ in,
                                                 unsigned short* __restrict__ out,
                                                 long n) {
  const long i = (long)blockIdx.x * 256 + threadIdx.x;
  if (i < n) out[i] = f2bf(in[i]);
}

// ------- pack weights [nRel blocks of K*H] + loopW[K*H] into B-frag layout --
__global__ __launch_bounds__(256) void prep_w_k(
    const float* __restrict__ Wr, const float* __restrict__ loopW,
    unsigned short* __restrict__ Bpre, int K, int colTiles, int nRel)
{
  const int idx = blockIdx.x * 256 + threadIdx.x;
  const int kSteps = K / 32;
  const int total = colTiles * kSteps * 64;
  if (idx >= total) return;
  const int lane = idx & 63;
  const int s    = (idx >> 6) % kSteps;
  const int Ct   = idx / (kSteps * 64);
  const int col  = Ct * 16 + (lane & 15);
  const int g    = col >> 7;
  const int cg   = col & 127;
  const float* src = (g < nRel) ? (Wr + (size_t)g * K * H + cg)
                                : (loopW + cg);
  const int k0 = s * 32 + (lane >> 4) * 8;
  unsigned short v[8];
#pragma unroll
  for (int j = 0; j < 8; ++j) v[j] = f2bf(src[(size_t)(k0 + j) * H]);
  unsigned short* dst = Bpre + (size_t)(((Ct * kSteps + s) * 64 + lane)) * 8;
  *(uint4*)dst = *(uint4*)v;
}

// ------------- fused MFMA GEMM, all col-groups per block --------------------
// grid.x = row tiles of 128. For g < fpGroup: bf16 into tmp_all[g];
// g == fpGroup: fp32 into agg + bias.
template<int KSTEPS>
__global__ __launch_bounds__(256) void mfma_gemm_t(
    const unsigned short* __restrict__ Abf,   // [M][K] bf16 row-major
    const unsigned short* __restrict__ Bpre,
    const float* __restrict__ bias,
    unsigned short* __restrict__ tmp_all,     // [fpGroup][M][H] bf16
    float* __restrict__ agg,                  // [M][H] fp32
    int M, int nGroups, int fpGroup)
{
  constexpr int K = KSTEPS * 32;
  constexpr int strideL = K + 8;
  __shared__ unsigned short Alds[128 * strideL];
  const int tid = threadIdx.x;
  const int rowBase = blockIdx.x * 128;

  constexpr int cpr = K / 8;                  // 16B chunks per row
  for (int c = tid; c < 128 * cpr; c += 256) {
    const int row = c / cpr;
    const int kc  = c % cpr;
    const int grow = rowBase + row;
    uint4 v = make_uint4(0, 0, 0, 0);
    if (grow < M) v = *(const uint4*)(Abf + (size_t)grow * K + kc * 8);
    *(uint4*)(Alds + (size_t)row * strideL + kc * 8) = v;
  }
  __syncthreads();

  const int wave = tid >> 6, lane = tid & 63;
  const int quad = lane >> 4, l15 = lane & 15;

  bf16x8 a[2][KSTEPS];
#pragma unroll
  for (int rt = 0; rt < 2; ++rt) {
    const int row = wave * 32 + rt * 16 + l15;
#pragma unroll
    for (int s = 0; s < KSTEPS; ++s)
      a[rt][s] = *(const bf16x8*)(Alds + (size_t)row * strideL + s * 32 + quad * 8);
  }

  for (int g = 0; g < nGroups; ++g) {
    f32x4 acc[2][8] = {};
    const unsigned short* bp = Bpre + ((size_t)g * 8) * KSTEPS * 64 * 8;
#pragma unroll
    for (int s = 0; s < KSTEPS; ++s) {
#pragma unroll
      for (int c = 0; c < 8; ++c) {
        const bf16x8 b = *(const bf16x8*)(bp + (size_t)((c * KSTEPS + s) * 64 + lane) * 8);
        acc[0][c] = __builtin_amdgcn_mfma_f32_16x16x32_bf16(a[0][s], b, acc[0][c], 0, 0, 0);
        acc[1][c] = __builtin_amdgcn_mfma_f32_16x16x32_bf16(a[1][s], b, acc[1][c], 0, 0, 0);
      }
    }
    if (g < fpGroup) {
      unsigned short* outp = tmp_all + (size_t)g * M * H;
#pragma unroll
      for (int rt = 0; rt < 2; ++rt)
#pragma unroll
        for (int reg = 0; reg < 4; ++reg) {
          const int row = rowBase + wave * 32 + rt * 16 + quad * 4 + reg;
          if (row >= M) continue;
#pragma unroll
          for (int c = 0; c < 8; ++c)
            outp[(size_t)row * H + c * 16 + l15] = f2bf(acc[rt][c][reg]);
        }
    } else {
#pragma unroll
      for (int rt = 0; rt < 2; ++rt)
#pragma unroll
        for (int reg = 0; reg < 4; ++reg) {
          const int row = rowBase + wave * 32 + rt * 16 + quad * 4 + reg;
          if (row >= M) continue;
#pragma unroll
          for (int c = 0; c < 8; ++c) {
            const int col = c * 16 + l15;
            agg[(size_t)row * H + col] = acc[rt][c][reg] + bias[col];
          }
        }
    }
  }
}

// ----------------------------- CSR build ------------------------------------
__global__ void zero_int_k(int* p, int n) {
  const int i = blockIdx.x * 256 + threadIdx.x;
  if (i < n) p[i] = 0;
}
__global__ void zero_k(float* p, int n) {
  const int i = blockIdx.x * 256 + threadIdx.x;
  if (i < n) p[i] = 0.f;
}

__global__ __launch_bounds__(256) void hist_k(const int* __restrict__ dst, int E,
                                              int* __restrict__ counts) {
  const int e = blockIdx.x * 256 + threadIdx.x;
  if (e < E) atomicAdd(&counts[dst[e]], 1);
}

__global__ __launch_bounds__(256) void scan1_k(const int* __restrict__ counts,
                                               int* __restrict__ rowp,
                                               int* __restrict__ partials, int n) {
  __shared__ int s[256];
  const int t = threadIdx.x, i = blockIdx.x * 256 + t;
  const int x = (i < n) ? counts[i] : 0;
  s[t] = x; __syncthreads();
  for (int off = 1; off < 256; off <<= 1) {
    const int v = (t >= off) ? s[t - off] : 0;
    __syncthreads(); s[t] += v; __syncthreads();
  }
  if (i < n) rowp[i] = s[t] - x;
  if (t == 255) partials[blockIdx.x] = s[255];
}

__global__ __launch_bounds__(512) void scan2_k(int* partials, int nb) {
  __shared__ int s[512];
  const int t = threadIdx.x;
  const int x = (t < nb) ? partials[t] : 0;
  s[t] = x; __syncthreads();
  for (int off = 1; off < 512; off <<= 1) {
    const int v = (t >= off) ? s[t - off] : 0;
    __syncthreads(); s[t] += v; __syncthreads();
  }
  if (t < nb) partials[t] = s[t] - x;
}

// finalize rowp, init per-node cursor (fallback) and per-bucket cursor
__global__ __launch_bounds__(256) void scan3_k(int* __restrict__ rowp,
                                               int* __restrict__ cursor,
                                               const int* __restrict__ partials,
                                               int* __restrict__ bcur,
                                               int n, int E) {
  const int i = blockIdx.x * 256 + threadIdx.x;
  if (i < n) {
    const int v = rowp[i] + partials[i >> 8];
    rowp[i] = v; cursor[i] = v;
    if ((i & 127) == 0) bcur[i >> 7] = v;
  }
  if (i == 0) rowp[n] = E;
}

// pass 1: append packed edge to its dst-bucket log (cache-friendly appends)
__global__ __launch_bounds__(256) void pack_bucket_k(
    const int* __restrict__ src, const int* __restrict__ dst,
    const int* __restrict__ et, int E,
    int* __restrict__ bcur, int* __restrict__ ep_log)
{
  const int e = blockIdx.x * 256 + threadIdx.x;
  if (e < E) {
    const int d = dst[e];
    const int val = ((d & 127) << 19) | (et[e] << 17) | src[e];
    const int pos = atomicAdd(&bcur[d >> 7], 1);
    ep_log[pos] = val;
  }
}

// pass 2: within-bucket counting sort (LDS) -> final CSR edge array
__global__ __launch_bounds__(256) void bucket_sort_k(
    const int* __restrict__ rowp, const int* __restrict__ ep_log,
    int* __restrict__ ep, int* __restrict__ cursor, int Nn)
{
  __shared__ int ent[8192];
  __shared__ int cnt[128];
  __shared__ int base[128];
  const int b = blockIdx.x;
  const int nodeBase = b << 7;
  const int nTop = min(nodeBase + 128, Nn);
  const int beg = rowp[nodeBase], end = rowp[nTop];
  const int cntE = end - beg;
  const int tid = threadIdx.x;
  if (cntE <= 8192) {
    for (int i = tid; i < cntE; i += 256) ent[i] = ep_log[beg + i];
    if (tid < 128) cnt[tid] = 0;
    __syncthreads();
    for (int i = tid; i < cntE; i += 256) atomicAdd(&cnt[ent[i] >> 19], 1);
    __syncthreads();
    if (tid == 0) {
      int s = 0;
      for (int i = 0; i < 128; ++i) { base[i] = s; s += cnt[i]; }
    }
    __syncthreads();
    for (int i = tid; i < cntE; i += 256) {
      const int v = ent[i];
      const int pos = atomicAdd(&base[v >> 19], 1);
      ep[beg + pos] = v & 0x7FFFF;
    }
  } else {   // overflow fallback (statistically unreachable): global cursors
    for (int i = tid; i < cntE; i += 256) {
      const int v = ep_log[beg + i];
      const int d = nodeBase + (v >> 19);
      const int pos = atomicAdd(&cursor[d], 1);
      ep[pos] = v & 0x7FFFF;
    }
  }
}

// legacy direct pack (only if encoding limits exceeded)
__global__ __launch_bounds__(256) void pack_k(const int* __restrict__ src,
                                              const int* __restrict__ dst,
                                              const int* __restrict__ et, int E,
                                              int* __restrict__ cursor,
                                              int* __restrict__ ep) {
  const int e = blockIdx.x * 256 + threadIdx.x;
  if (e < E) {
    const int pos = atomicAdd(&cursor[dst[e]], 1);
    ep[pos] = (et[e] << 20) | src[e];
  }
}

// ----- CSR gather (bf16 messages): agg[n] += sum tmp_all[et][src] -----------
__global__ __launch_bounds__(256) void gather_csr_k(
    const unsigned short* __restrict__ tmp_all, const int* __restrict__ rowp,
    const int* __restrict__ ep, float* __restrict__ agg, int Nn,
    int etShift, int srcMask)
{
  const int node = (blockIdx.x * 256 + threadIdx.x) >> 6;
  const int lane = threadIdx.x & 63;
  if (node >= Nn) return;
  const int beg = rowp[node], end = rowp[node + 1];
  float2 acc = ((const float2*)(agg + (size_t)node * H))[lane];
  int e = beg;
  for (; e + 3 < end; e += 4) {
    unsigned v[4];
#pragma unroll
    for (int j = 0; j < 4; ++j) {
      const int p = ep[e + j];
      v[j] = *(const unsigned*)(tmp_all +
          ((size_t)(p >> etShift) * Nn + (p & srcMask)) * H + lane * 2);
    }
#pragma unroll
    for (int j = 0; j < 4; ++j) {
      acc.x += bf2f((unsigned short)(v[j] & 0xFFFF));
      acc.y += bf2f((unsigned short)(v[j] >> 16));
    }
  }
  for (; e < end; ++e) {
    const int p = ep[e];
    const unsigned v = *(const unsigned*)(tmp_all +
        ((size_t)(p >> etShift) * Nn + (p & srcMask)) * H + lane * 2);
    acc.x += bf2f((unsigned short)(v & 0xFFFF));
    acc.y += bf2f((unsigned short)(v >> 16));
  }
  ((float2*)(agg + (size_t)node * H))[lane] = acc;
}

// ---------------------------- BN helpers ------------------------------------
__global__ __launch_bounds__(256) void bn_stats_k(
    const float* __restrict__ X, int Nn, float* __restrict__ stats)
{
  const int col  = threadIdx.x & 127;
  const int half = threadIdx.x >> 7;
  float s = 0.f, q = 0.f;
  for (int row = blockIdx.x * 2 + half; row < Nn; row += gridDim.x * 2) {
    const float v = X[(size_t)row * H + col];
    s += v; q += v * v;
  }
  __shared__ float ls[256], lq[256];
  ls[threadIdx.x] = s; lq[threadIdx.x] = q;
  __syncthreads();
  if (threadIdx.x < 128) {
    atomicAdd(&stats[col],     ls[threadIdx.x] + ls[threadIdx.x + 128]);
    atomicAdd(&stats[H + col], lq[threadIdx.x] + lq[threadIdx.x + 128]);
  }
}

__global__ __launch_bounds__(256) void bn_apply_k(
    const float* __restrict__ X, const float* __restrict__ stats,
    const float* __restrict__ gamma, const float* __restrict__ beta,
    unsigned short* __restrict__ out_bf, float* __restrict__ out_f,
    int Nn, int relu)
{
  const size_t i = (size_t)blockIdx.x * 256 + threadIdx.x;
  const size_t total = (size_t)Nn * H;
  if (i >= total) return;
  const int col = (int)(i & 127);
  const float mu  = stats[col] / Nn;
  const float var = stats[H + col] / Nn - mu * mu;
  const float inv = rsqrtf(var + 1e-5f);
  float v = fmaf(gamma[col] * inv, X[i] - mu, beta[col]);
  if (relu) v = fmaxf(v, 0.f);
  if (out_bf) out_bf[i] = f2bf(v);
  else        out_f[i]  = v;
}

// ---------------------------------------------------------------------------
extern "C" void kernel_launch(void* const* d_in, const int* in_sizes, int n_in,
                              void* d_out, int out_size, void* d_ws, size_t ws_size,
                              hipStream_t stream)
{
  const float* x     = (const float*)d_in[0];
  const int*   src   = (const int*)d_in[1];
  const int*   dst   = (const int*)d_in[2];
  const int*   et    = (const int*)d_in[3];
  const float* W0    = (const float*)d_in[4];
  const float* loop0 = (const float*)d_in[5];
  const float* b0    = (const float*)d_in[6];
  const float* g0    = (const float*)d_in[7];
  const float* be0   = (const float*)d_in[8];
  const float* Ws    = (const float*)d_in[9];
  const float* loops = (const float*)d_in[10];
  const float* bs    = (const float*)d_in[11];
  const float* gs    = (const float*)d_in[12];
  const float* bes   = (const float*)d_in[13];
  const float* Wl    = (const float*)d_in[14];
  const float* bl    = (const float*)d_in[15];
  const float* gl    = (const float*)d_in[16];
  const float* bel   = (const float*)d_in[17];

  const int E = in_sizes[1];
  const int F_in = 64;
  const int N = in_sizes[0] / F_in;
  const int R = in_sizes[4] / (F_in * H);
  const int L = in_sizes[9] / (R * H * H);

  float* outp = (float*)d_out;

  // ---- workspace layout ----
  char* p = (char*)d_ws;
  auto alloc = [&](size_t bytes) { char* r = p; p += (bytes + 255) & ~size_t(255); return r; };
  const int nbuckets = (N + 127) / 128;
  const int c0 = (R + 1) * 8 * (F_in / 32) * 64;   // frag counts
  const int ch = (R + 1) * 8 * (H / 32) * 64;
  const int cf = 8 * (H / 32) * 64;
  float*          agg      = (float*)alloc((size_t)N * H * 4);
  float*          stats    = (float*)alloc((size_t)(L + 2) * 2 * H * 4);
  unsigned short* tmp_all  = (unsigned short*)alloc((size_t)R * N * H * 2);
  unsigned short* hbf      = (unsigned short*)alloc((size_t)N * H * 2);
  unsigned short* Bpre_all = (unsigned short*)alloc((size_t)(c0 + L * ch + cf) * 8 * 2);
  int*            counts   = (int*)alloc((size_t)N * 4);
  int*            rowp     = (int*)alloc((size_t)(N + 1) * 4);
  int*            cursor   = (int*)alloc((size_t)N * 4);
  int*            partials = (int*)alloc(512 * 4);
  int*            bcur     = (int*)alloc((size_t)nbuckets * 4);
  int*            ep       = (int*)alloc((size_t)E * 4);
  int*            ep_log   = (int*)alloc((size_t)E * 4);
  (void)ws_size;

  const int eblocks = (E + 255) / 256;
  const int nblocks = (N + 255) / 256;
  const size_t tot = (size_t)N * H;
  const int apply_blocks = (int)((tot + 255) / 256);
  const int rowBlocks = (N + 127) / 128;
  const bool fast_enc = (N < (1 << 17)) && (R <= 4);
  const int etShift = fast_enc ? 17 : 20;
  const int srcMask = fast_enc ? 0x1FFFF : 0xFFFFF;

  // ---- prepack all weights (bf16 B-fragment layout) ----
  {
    hipLaunchKernelGGL(prep_w_k, dim3((c0 + 255) / 256), dim3(256), 0, stream,
                       W0, loop0, Bpre_all, F_in, (R + 1) * 8, R);
    for (int l = 0; l < L; ++l)
      hipLaunchKernelGGL(prep_w_k, dim3((ch + 255) / 256), dim3(256), 0, stream,
                         Ws + (size_t)l * R * H * H, loops + (size_t)l * H * H,
                         Bpre_all + (size_t)(c0 + l * ch) * 8, H, (R + 1) * 8, R);
    hipLaunchKernelGGL(prep_w_k, dim3((cf + 255) / 256), dim3(256), 0, stream,
                       (const float*)nullptr, Wl,
                       Bpre_all + (size_t)(c0 + L * ch) * 8, H, 8, 0);
  }

  // ---- convert x to bf16; zero stats + counts ----
  {
    const long nx = (long)N * F_in;
    hipLaunchKernelGGL(conv_bf_k, dim3((unsigned)((nx + 255) / 256)), dim3(256), 0, stream,
                       x, hbf, nx);
  }
  hipLaunchKernelGGL(zero_k, dim3(((L + 2) * 2 * H + 255) / 256), dim3(256), 0, stream,
                     stats, (L + 2) * 2 * H);
  hipLaunchKernelGGL(zero_int_k, dim3(nblocks), dim3(256), 0, stream, counts, N);

  // ---- build dst-CSR ----
  hipLaunchKernelGGL(hist_k, dim3(eblocks), dim3(256), 0, stream, dst, E, counts);
  hipLaunchKernelGGL(scan1_k, dim3(nblocks), dim3(256), 0, stream, counts, rowp, partials, N);
  hipLaunchKernelGGL(scan2_k, dim3(1), dim3(512), 0, stream, partials, nblocks);
  hipLaunchKernelGGL(scan3_k, dim3(nblocks), dim3(256), 0, stream, rowp, cursor, partials, bcur, N, E);
  if (fast_enc) {
    hipLaunchKernelGGL(pack_bucket_k, dim3(eblocks), dim3(256), 0, stream,
                       src, dst, et, E, bcur, ep_log);
    hipLaunchKernelGGL(bucket_sort_k, dim3(nbuckets), dim3(256), 0, stream,
                       rowp, ep_log, ep, cursor, N);
  } else {
    hipLaunchKernelGGL(pack_k, dim3(eblocks), dim3(256), 0, stream, src, dst, et, E, cursor, ep);
  }

  auto run_layer = [&](const unsigned short* Abf, int layerIdx, int K,
                       const float* bias, const float* gamma, const float* beta) {
    const unsigned short* Bp = Bpre_all +
        (size_t)((layerIdx == 0) ? 0 : (c0 + (layerIdx - 1) * ch)) * 8;
    float* st = stats + (size_t)layerIdx * 2 * H;
    if (K == 64)
      hipLaunchKernelGGL(mfma_gemm_t<2>, dim3(rowBlocks), dim3(256), 0, stream,
                         Abf, Bp, bias, tmp_all, agg, N, R + 1, R);
    else
      hipLaunchKernelGGL(mfma_gemm_t<4>, dim3(rowBlocks), dim3(256), 0, stream,
                         Abf, Bp, bias, tmp_all, agg, N, R + 1, R);
    hipLaunchKernelGGL(gather_csr_k, dim3((N + 3) / 4), dim3(256), 0, stream,
                       tmp_all, rowp, ep, agg, N, etShift, srcMask);
    hipLaunchKernelGGL(bn_stats_k, dim3(512), dim3(256), 0, stream, agg, N, st);
    hipLaunchKernelGGL(bn_apply_k, dim3(apply_blocks), dim3(256), 0, stream,
                       agg, st, gamma, beta, hbf, (float*)nullptr, N, 1);
  };

  run_layer(hbf, 0, F_in, b0, g0, be0);
  for (int l = 0; l < L; ++l)
    run_layer(hbf, 1 + l, H, bs + l * H, gs + l * H, bes + l * H);

  // ---- final linear + BN (no ReLU) -> d_out ----
  {
    float* st = stats + (size_t)(L + 1) * 2 * H;
    hipLaunchKernelGGL(mfma_gemm_t<4>, dim3(rowBlocks), dim3(256), 0, stream,
                       hbf, Bpre_all + (size_t)(c0 + L * ch) * 8, bl,
                       (unsigned short*)nullptr, agg, N, 1, 0);
    hipLaunchKernelGGL(bn_stats_k, dim3(512), dim3(256), 0, stream, agg, N, st);
    hipLaunchKernelGGL(bn_apply_k, dim3(apply_blocks), dim3(256), 0, stream,
                       agg, st, gl, bel, (unsigned short*)nullptr, outp, N, 0);
  }
}

// Round 5
// 1020.796 us; speedup vs baseline: 1.2370x; 1.2370x over previous
//
#include <hip/hip_runtime.h>

constexpr int H = 128;        // hidden width
constexpr int EPB = 8192;     // edges per partition block
constexpr int BSH = 8;        // bucket shift: 256 nodes / bucket

typedef __attribute__((ext_vector_type(8))) __bf16 bf16x8;
typedef __attribute__((ext_vector_type(4))) float  f32x4;

__device__ __forceinline__ unsigned short f2bf(float f) {
  unsigned u = __builtin_bit_cast(unsigned, f);
  u += 0x7FFFu + ((u >> 16) & 1u);          // RNE
  return (unsigned short)(u >> 16);
}
__device__ __forceinline__ float bf2f(unsigned short b) {
  unsigned u = ((unsigned)b) << 16;
  return __builtin_bit_cast(float, u);
}

__global__ void zero_k(float* p, int n) {
  const int i = blockIdx.x * 256 + threadIdx.x;
  if (i < n) p[i] = 0.f;
}

// ------- pack weights [nRel blocks of K*H] + loopW[K*H] into B-frag layout --
__global__ __launch_bounds__(256) void prep_w_k(
    const float* __restrict__ Wr, const float* __restrict__ loopW,
    unsigned short* __restrict__ Bpre, int K, int colTiles, int nRel)
{
  const int idx = blockIdx.x * 256 + threadIdx.x;
  const int kSteps = K / 32;
  const int total = colTiles * kSteps * 64;
  if (idx >= total) return;
  const int lane = idx & 63;
  const int s    = (idx >> 6) % kSteps;
  const int Ct   = idx / (kSteps * 64);
  const int col  = Ct * 16 + (lane & 15);
  const int g    = col >> 7;
  const int cg   = col & 127;
  const float* src = (g < nRel) ? (Wr + (size_t)g * K * H + cg) : (loopW + cg);
  const int k0 = s * 32 + (lane >> 4) * 8;
  unsigned short v[8];
#pragma unroll
  for (int j = 0; j < 8; ++j) v[j] = f2bf(src[(size_t)(k0 + j) * H]);
  unsigned short* dst = Bpre + (size_t)(((Ct * kSteps + s) * 64 + lane)) * 8;
  *(uint4*)dst = *(uint4*)v;
}

// ---------------- partition stage A: per-bucket totals ----------------------
__global__ __launch_bounds__(256) void bucket_hist_k(
    const int* __restrict__ dst, int E, int* __restrict__ gcnt, int nbuckets)
{
  __shared__ int cnt[512];
  const int tid = threadIdx.x;
  for (int b = tid; b < nbuckets; b += 256) cnt[b] = 0;
  __syncthreads();
  const int base = blockIdx.x * EPB;
  for (int j = tid; j < EPB; j += 256) {
    const int e = base + j;
    if (e < E) atomicAdd(&cnt[dst[e] >> BSH], 1);
  }
  __syncthreads();
  for (int b = tid; b < nbuckets; b += 256)
    if (cnt[b]) atomicAdd(&gcnt[b], cnt[b]);
}

// ---------------- partition stage B: scan buckets, init padded cursors ------
__global__ __launch_bounds__(512) void bucket_scan_k(
    const int* __restrict__ gcnt, int* __restrict__ boffs,
    int* __restrict__ pcur, int nbuckets, int E)
{
  __shared__ int s[512];
  const int t = threadIdx.x;
  const int x = (t < nbuckets) ? gcnt[t] : 0;
  s[t] = x; __syncthreads();
  for (int off = 1; off < 512; off <<= 1) {
    const int v = (t >= off) ? s[t - off] : 0;
    __syncthreads(); s[t] += v; __syncthreads();
  }
  if (t < nbuckets) {
    const int excl = s[t] - x;
    boffs[t] = excl;
    pcur[t * 16] = excl;          // 64B-padded cursor: own cache line
  }
  if (t == 0) boffs[nbuckets] = E;
}

// ---------------- partition stage C: block-aggregated bucket append ---------
__global__ __launch_bounds__(256) void pack2_k(
    const int* __restrict__ src, const int* __restrict__ dst,
    const int* __restrict__ et, int E,
    int* __restrict__ pcur, int* __restrict__ ep_log, int nbuckets)
{
  __shared__ int cnt[512];
  __shared__ int basel[512];
  __shared__ unsigned short ranks[EPB];
  const int tid = threadIdx.x;
  for (int b = tid; b < nbuckets; b += 256) cnt[b] = 0;
  __syncthreads();
  const int base = blockIdx.x * EPB;
  for (int j = tid; j < EPB; j += 256) {
    const int e = base + j;
    if (e < E) ranks[j] = (unsigned short)atomicAdd(&cnt[dst[e] >> BSH], 1);
  }
  __syncthreads();
  for (int b = tid; b < nbuckets; b += 256)
    basel[b] = cnt[b] ? atomicAdd(&pcur[b * 16], cnt[b]) : 0;
  __syncthreads();
  for (int j = tid; j < EPB; j += 256) {
    const int e = base + j;
    if (e < E) {
      const int d = dst[e];
      const int pos = basel[d >> BSH] + ranks[j];
      ep_log[pos] = ((d & 255) << 19) | (et[e] << 17) | src[e];
    }
  }
}

// ------- partition stage D: per-bucket counting sort -> ep + rowp -----------
__global__ __launch_bounds__(256) void bucket_sort2_k(
    const int* __restrict__ boffs, const int* __restrict__ ep_log,
    int* __restrict__ ep, int* __restrict__ rowp, int Nn, int E)
{
  __shared__ int ent[EPB];
  __shared__ int cntA[256];
  __shared__ int curA[256];
  const int b = blockIdx.x;
  const int tid = threadIdx.x;
  const int beg = boffs[b], end = boffs[b + 1];
  const int n = end - beg;
  const bool inl = (n <= EPB);
  if (inl) for (int i = tid; i < n; i += 256) ent[i] = ep_log[beg + i];
  cntA[tid] = 0;
  __syncthreads();
  for (int i = tid; i < n; i += 256) {
    const int v = inl ? ent[i] : ep_log[beg + i];
    atomicAdd(&cntA[v >> 19], 1);
  }
  __syncthreads();
  const int my = cntA[tid];
  for (int off = 1; off < 256; off <<= 1) {       // inclusive scan
    const int v = (tid >= off) ? cntA[tid - off] : 0;
    __syncthreads(); cntA[tid] += v; __syncthreads();
  }
  const int excl = cntA[tid] - my;
  const int node = (b << BSH) + tid;
  if (node < Nn) rowp[node] = beg + excl;
  if (b == 0 && tid == 0) rowp[Nn] = E;
  curA[tid] = excl;
  __syncthreads();
  for (int i = tid; i < n; i += 256) {
    const int v = inl ? ent[i] : ep_log[beg + i];
    const int p = atomicAdd(&curA[v >> 19], 1);
    ep[beg + p] = v & 0x7FFFF;                    // (et<<17)|src
  }
}

// ------------- fused MFMA GEMM, all col-groups per block --------------------
// BN==1: stage A from fp32 agg applying y = relu(s*x + t) per column.
// BN==0: stage A from fp32 x with plain convert.
template<int KSTEPS, int BN>
__global__ __launch_bounds__(256) void mfma_gemm_t(
    const float* __restrict__ Af,             // [M][K] fp32
    const unsigned short* __restrict__ Bpre,
    const float* __restrict__ bias,
    const float* __restrict__ stats,          // 2*H sums (BN==1)
    const float* __restrict__ gamma, const float* __restrict__ beta,
    unsigned short* __restrict__ tmp_all,     // [fpGroup][M][H] bf16
    float* __restrict__ agg,                  // [M][H] fp32 out
    int M, int nGroups, int fpGroup, float invN)
{
  constexpr int K = KSTEPS * 32;
  constexpr int strideL = K + 8;
  __shared__ unsigned short Alds[128 * strideL];
  __shared__ float sbt[128], tbt[128];
  const int tid = threadIdx.x;
  const int rowBase = blockIdx.x * 128;

  if (BN) {
    if (tid < 128) {
      const float mu  = stats[tid] * invN;
      const float var = stats[128 + tid] * invN - mu * mu;
      const float s = gamma[tid] * rsqrtf(var + 1e-5f);
      sbt[tid] = s; tbt[tid] = beta[tid] - s * mu;
    }
    __syncthreads();
  }

  constexpr int cpr4 = K / 4;                 // float4 chunks per row
  for (int c = tid; c < 128 * cpr4; c += 256) {
    const int row = c / cpr4;
    const int k4  = c % cpr4;
    const int grow = rowBase + row;
    float4 v = make_float4(0.f, 0.f, 0.f, 0.f);
    if (grow < M) v = *(const float4*)(Af + (size_t)grow * K + k4 * 4);
    unsigned short o[4];
    if (BN) {
      const int col = k4 * 4;
      o[0] = f2bf(fmaxf(fmaf(sbt[col+0], v.x, tbt[col+0]), 0.f));
      o[1] = f2bf(fmaxf(fmaf(sbt[col+1], v.y, tbt[col+1]), 0.f));
      o[2] = f2bf(fmaxf(fmaf(sbt[col+2], v.z, tbt[col+2]), 0.f));
      o[3] = f2bf(fmaxf(fmaf(sbt[col+3], v.w, tbt[col+3]), 0.f));
    } else {
      o[0] = f2bf(v.x); o[1] = f2bf(v.y); o[2] = f2bf(v.z); o[3] = f2bf(v.w);
    }
    *(uint2*)(Alds + (size_t)row * strideL + k4 * 4) = *(uint2*)o;
  }
  __syncthreads();

  const int wave = tid >> 6, lane = tid & 63;
  const int quad = lane >> 4, l15 = lane & 15;

  bf16x8 a[2][KSTEPS];
#pragma unroll
  for (int rt = 0; rt < 2; ++rt) {
    const int row = wave * 32 + rt * 16 + l15;
#pragma unroll
    for (int s = 0; s < KSTEPS; ++s)
      a[rt][s] = *(const bf16x8*)(Alds + (size_t)row * strideL + s * 32 + quad * 8);
  }

  for (int g = 0; g < nGroups; ++g) {
    f32x4 acc[2][8] = {};
    const unsigned short* bp = Bpre + ((size_t)g * 8) * KSTEPS * 64 * 8;
#pragma unroll
    for (int s = 0; s < KSTEPS; ++s) {
#pragma unroll
      for (int c = 0; c < 8; ++c) {
        const bf16x8 b = *(const bf16x8*)(bp + (size_t)((c * KSTEPS + s) * 64 + lane) * 8);
        acc[0][c] = __builtin_amdgcn_mfma_f32_16x16x32_bf16(a[0][s], b, acc[0][c], 0, 0, 0);
        acc[1][c] = __builtin_amdgcn_mfma_f32_16x16x32_bf16(a[1][s], b, acc[1][c], 0, 0, 0);
      }
    }
    if (g < fpGroup) {
      unsigned short* outp = tmp_all + (size_t)g * M * H;
#pragma unroll
      for (int rt = 0; rt < 2; ++rt)
#pragma unroll
        for (int reg = 0; reg < 4; ++reg) {
          const int row = rowBase + wave * 32 + rt * 16 + quad * 4 + reg;
          if (row >= M) continue;
#pragma unroll
          for (int c = 0; c < 8; ++c)
            outp[(size_t)row * H + c * 16 + l15] = f2bf(acc[rt][c][reg]);
        }
    } else {
#pragma unroll
      for (int rt = 0; rt < 2; ++rt)
#pragma unroll
        for (int reg = 0; reg < 4; ++reg) {
          const int row = rowBase + wave * 32 + rt * 16 + quad * 4 + reg;
          if (row >= M) continue;
#pragma unroll
          for (int c = 0; c < 8; ++c) {
            const int col = c * 16 + l15;
            agg[(size_t)row * H + col] = acc[rt][c][reg] + bias[col];
          }
        }
    }
  }
}

// ----- CSR gather (bf16 messages) + fused BN-stats accumulation -------------
__global__ __launch_bounds__(256) void gather_csr_k(
    const unsigned short* __restrict__ tmp_all, const int* __restrict__ rowp,
    const int* __restrict__ ep, float* __restrict__ agg,
    float* __restrict__ stats, int Nn)
{
  __shared__ float sAcc[4][128];
  __shared__ float qAcc[4][128];
  const int tid = threadIdx.x;
  const int wave = tid >> 6, lane = tid & 63;
  sAcc[wave][lane] = 0.f;  sAcc[wave][64 + lane] = 0.f;
  qAcc[wave][lane] = 0.f;  qAcc[wave][64 + lane] = 0.f;

  const int waveId = blockIdx.x * 4 + wave;
  const int nWaves = gridDim.x * 4;
  for (int node = waveId; node < Nn; node += nWaves) {
    const int beg = rowp[node], end = rowp[node + 1];
    float2 acc = ((const float2*)(agg + (size_t)node * H))[lane];
    int e = beg;
    for (; e + 3 < end; e += 4) {
      unsigned v[4];
#pragma unroll
      for (int j = 0; j < 4; ++j) {
        const int p = ep[e + j];
        v[j] = *(const unsigned*)(tmp_all +
            ((size_t)(p >> 17) * Nn + (p & 0x1FFFF)) * H + lane * 2);
      }
#pragma unroll
      for (int j = 0; j < 4; ++j) {
        acc.x += bf2f((unsigned short)(v[j] & 0xFFFF));
        acc.y += bf2f((unsigned short)(v[j] >> 16));
      }
    }
    for (; e < end; ++e) {
      const int p = ep[e];
      const unsigned v = *(const unsigned*)(tmp_all +
          ((size_t)(p >> 17) * Nn + (p & 0x1FFFF)) * H + lane * 2);
      acc.x += bf2f((unsigned short)(v & 0xFFFF));
      acc.y += bf2f((unsigned short)(v >> 16));
    }
    ((float2*)(agg + (size_t)node * H))[lane] = acc;
    sAcc[wave][lane * 2]     += acc.x;
    sAcc[wave][lane * 2 + 1] += acc.y;
    qAcc[wave][lane * 2]     += acc.x * acc.x;
    qAcc[wave][lane * 2 + 1] += acc.y * acc.y;
  }
  __syncthreads();
  if (tid < 128) {
    float s = sAcc[0][tid] + sAcc[1][tid] + sAcc[2][tid] + sAcc[3][tid];
    atomicAdd(&stats[tid], s);
  } else {
    const int c = tid - 128;
    float q = qAcc[0][c] + qAcc[1][c] + qAcc[2][c] + qAcc[3][c];
    atomicAdd(&stats[128 + c], q);
  }
}

// ---------------------------- final BN helpers ------------------------------
__global__ __launch_bounds__(256) void bn_stats_k(
    const float* __restrict__ X, int Nn, float* __restrict__ stats)
{
  const int col  = threadIdx.x & 127;
  const int half = threadIdx.x >> 7;
  float s = 0.f, q = 0.f;
  for (int row = blockIdx.x * 2 + half; row < Nn; row += gridDim.x * 2) {
    const float v = X[(size_t)row * H + col];
    s += v; q += v * v;
  }
  __shared__ float ls[256], lq[256];
  ls[threadIdx.x] = s; lq[threadIdx.x] = q;
  __syncthreads();
  if (threadIdx.x < 128) {
    atomicAdd(&stats[col],     ls[threadIdx.x] + ls[threadIdx.x + 128]);
    atomicAdd(&stats[H + col], lq[threadIdx.x] + lq[threadIdx.x + 128]);
  }
}

__global__ __launch_bounds__(256) void bn_apply_k(
    const float* __restrict__ X, const float* __restrict__ stats,
    const float* __restrict__ gamma, const float* __restrict__ beta,
    float* __restrict__ out_f, int Nn)
{
  const size_t i = (size_t)blockIdx.x * 256 + threadIdx.x;
  const size_t total = (size_t)Nn * H;
  if (i >= total) return;
  const int col = (int)(i & 127);
  const float mu  = stats[col] / Nn;
  const float var = stats[H + col] / Nn - mu * mu;
  const float inv = rsqrtf(var + 1e-5f);
  out_f[i] = fmaf(gamma[col] * inv, X[i] - mu, beta[col]);
}

// ---------------------------------------------------------------------------
extern "C" void kernel_launch(void* const* d_in, const int* in_sizes, int n_in,
                              void* d_out, int out_size, void* d_ws, size_t ws_size,
                              hipStream_t stream)
{
  const float* x     = (const float*)d_in[0];
  const int*   src   = (const int*)d_in[1];
  const int*   dst   = (const int*)d_in[2];
  const int*   et    = (const int*)d_in[3];
  const float* W0    = (const float*)d_in[4];
  const float* loop0 = (const float*)d_in[5];
  const float* b0    = (const float*)d_in[6];
  const float* g0    = (const float*)d_in[7];
  const float* be0   = (const float*)d_in[8];
  const float* Ws    = (const float*)d_in[9];
  const float* loops = (const float*)d_in[10];
  const float* bs    = (const float*)d_in[11];
  const float* gs    = (const float*)d_in[12];
  const float* bes   = (const float*)d_in[13];
  const float* Wl    = (const float*)d_in[14];
  const float* bl    = (const float*)d_in[15];
  const float* gl    = (const float*)d_in[16];
  const float* bel   = (const float*)d_in[17];

  const int E = in_sizes[1];
  const int F_in = 64;
  const int N = in_sizes[0] / F_in;
  const int R = in_sizes[4] / (F_in * H);
  const int L = in_sizes[9] / (R * H * H);
  const float invN = 1.0f / (float)N;

  float* outp = (float*)d_out;

  // ---- workspace layout ----
  char* p = (char*)d_ws;
  auto alloc = [&](size_t bytes) { char* r = p; p += (bytes + 255) & ~size_t(255); return r; };
  const int nbuckets = (N + (1 << BSH) - 1) >> BSH;       // <= 512 (N<=131072)
  const int c0 = (R + 1) * 8 * (F_in / 32) * 64;
  const int ch = (R + 1) * 8 * (H / 32) * 64;
  const int cf = 8 * (H / 32) * 64;
  float*          agg      = (float*)alloc((size_t)N * H * 4);
  float*          stats    = (float*)alloc((size_t)(L + 2) * 2 * H * 4);
  unsigned short* tmp_all  = (unsigned short*)alloc((size_t)R * N * H * 2);
  unsigned short* Bpre_all = (unsigned short*)alloc((size_t)(c0 + L * ch + cf) * 8 * 2);
  int*            gcnt     = (int*)alloc((size_t)nbuckets * 4);
  int*            boffs    = (int*)alloc((size_t)(nbuckets + 1) * 4);
  int*            pcur     = (int*)alloc((size_t)nbuckets * 16 * 4);   // 64B padded
  int*            rowp     = (int*)alloc((size_t)(N + 1) * 4);
  int*            ep       = (int*)alloc((size_t)E * 4);
  int*            ep_log   = (int*)alloc((size_t)E * 4);
  (void)ws_size;

  const int pblocks = (E + EPB - 1) / EPB;
  const int rowBlocks = (N + 127) / 128;

  // ---- prepack all weights (bf16 B-fragment layout) ----
  hipLaunchKernelGGL(prep_w_k, dim3((c0 + 255) / 256), dim3(256), 0, stream,
                     W0, loop0, Bpre_all, F_in, (R + 1) * 8, R);
  for (int l = 0; l < L; ++l)
    hipLaunchKernelGGL(prep_w_k, dim3((ch + 255) / 256), dim3(256), 0, stream,
                       Ws + (size_t)l * R * H * H, loops + (size_t)l * H * H,
                       Bpre_all + (size_t)(c0 + l * ch) * 8, H, (R + 1) * 8, R);
  hipLaunchKernelGGL(prep_w_k, dim3((cf + 255) / 256), dim3(256), 0, stream,
                     (const float*)nullptr, Wl, Bpre_all + (size_t)(c0 + L * ch) * 8, H, 8, 0);

  // ---- zero stats + bucket counters ----
  hipLaunchKernelGGL(zero_k, dim3(((L + 2) * 2 * H + 255) / 256), dim3(256), 0, stream,
                     stats, (L + 2) * 2 * H);
  hipLaunchKernelGGL(zero_k, dim3((nbuckets + 255) / 256), dim3(256), 0, stream,
                     (float*)gcnt, nbuckets);

  // ---- partition: hist -> scan -> pack -> per-bucket sort ----
  hipLaunchKernelGGL(bucket_hist_k, dim3(pblocks), dim3(256), 0, stream, dst, E, gcnt, nbuckets);
  hipLaunchKernelGGL(bucket_scan_k, dim3(1), dim3(512), 0, stream, gcnt, boffs, pcur, nbuckets, E);
  hipLaunchKernelGGL(pack2_k, dim3(pblocks), dim3(256), 0, stream,
                     src, dst, et, E, pcur, ep_log, nbuckets);
  hipLaunchKernelGGL(bucket_sort2_k, dim3(nbuckets), dim3(256), 0, stream,
                     boffs, ep_log, ep, rowp, N, E);

  // ---- layer 0: GEMM from x (no BN), gather w/ fused stats ----
  hipLaunchKernelGGL((mfma_gemm_t<2, 0>), dim3(rowBlocks), dim3(256), 0, stream,
                     x, Bpre_all, b0, (const float*)nullptr,
                     (const float*)nullptr, (const float*)nullptr,
                     tmp_all, agg, N, R + 1, R, invN);
  hipLaunchKernelGGL(gather_csr_k, dim3(512), dim3(256), 0, stream,
                     tmp_all, rowp, ep, agg, stats, N);

  // ---- hidden conv layers: BN(prev) fused into GEMM A-staging ----
  for (int l = 0; l < L; ++l) {
    const float* gam = (l == 0) ? g0 : gs + (size_t)(l - 1) * H;
    const float* bet = (l == 0) ? be0 : bes + (size_t)(l - 1) * H;
    hipLaunchKernelGGL((mfma_gemm_t<4, 1>), dim3(rowBlocks), dim3(256), 0, stream,
                       agg, Bpre_all + (size_t)(c0 + l * ch) * 8, bs + (size_t)l * H,
                       stats + (size_t)l * 2 * H, gam, bet,
                       tmp_all, agg, N, R + 1, R, invN);
    hipLaunchKernelGGL(gather_csr_k, dim3(512), dim3(256), 0, stream,
                       tmp_all, rowp, ep, agg, stats + (size_t)(l + 1) * 2 * H, N);
  }

  // ---- final linear (BN(last conv) fused) + final BN -> d_out ----
  {
    const float* gam = (L == 0) ? g0 : gs + (size_t)(L - 1) * H;
    const float* bet = (L == 0) ? be0 : bes + (size_t)(L - 1) * H;
    float* stF = stats + (size_t)(L + 1) * 2 * H;
    hipLaunchKernelGGL((mfma_gemm_t<4, 1>), dim3(rowBlocks), dim3(256), 0, stream,
                       agg, Bpre_all + (size_t)(c0 + L * ch) * 8, bl,
                       stats + (size_t)L * 2 * H, gam, bet,
                       (unsigned short*)nullptr, agg, N, 1, 0, invN);
    hipLaunchKernelGGL(bn_stats_k, dim3(512), dim3(256), 0, stream, agg, N, stF);
    const int apply_blocks = (int)(((size_t)N * H + 255) / 256);
    hipLaunchKernelGGL(bn_apply_k, dim3(apply_blocks), dim3(256), 0, stream,
                       agg, stF, gl, bel, outp, N);
  }
}

// Round 6
// 700.118 us; speedup vs baseline: 1.8036x; 1.4580x over previous
//
#include <hip/hip_runtime.h>

constexpr int H = 128;        // hidden width
constexpr int EPB = 8192;     // edges per partition block
constexpr int BSH = 8;        // bucket shift: 256 nodes / bucket
constexpr int NSHADOW = 32;   // stats shadow copies (atomic de-contention)

typedef __attribute__((ext_vector_type(8))) __bf16 bf16x8;
typedef __attribute__((ext_vector_type(4))) float  f32x4;

__device__ __forceinline__ unsigned short f2bf(float f) {
  unsigned u = __builtin_bit_cast(unsigned, f);
  u += 0x7FFFu + ((u >> 16) & 1u);          // RNE
  return (unsigned short)(u >> 16);
}
__device__ __forceinline__ float bf2f(unsigned short b) {
  unsigned u = ((unsigned)b) << 16;
  return __builtin_bit_cast(float, u);
}

__global__ void zero_k(float* p, int n) {
  const int i = blockIdx.x * 256 + threadIdx.x;
  if (i < n) p[i] = 0.f;
}

// ------- pack weights [nRel blocks of K*H] + loopW[K*H] into B-frag layout --
__global__ __launch_bounds__(256) void prep_w_k(
    const float* __restrict__ Wr, const float* __restrict__ loopW,
    unsigned short* __restrict__ Bpre, int K, int colTiles, int nRel)
{
  const int idx = blockIdx.x * 256 + threadIdx.x;
  const int kSteps = K / 32;
  const int total = colTiles * kSteps * 64;
  if (idx >= total) return;
  const int lane = idx & 63;
  const int s    = (idx >> 6) % kSteps;
  const int Ct   = idx / (kSteps * 64);
  const int col  = Ct * 16 + (lane & 15);
  const int g    = col >> 7;
  const int cg   = col & 127;
  const float* src = (g < nRel) ? (Wr + (size_t)g * K * H + cg) : (loopW + cg);
  const int k0 = s * 32 + (lane >> 4) * 8;
  unsigned short v[8];
#pragma unroll
  for (int j = 0; j < 8; ++j) v[j] = f2bf(src[(size_t)(k0 + j) * H]);
  unsigned short* dst = Bpre + (size_t)(((Ct * kSteps + s) * 64 + lane)) * 8;
  *(uint4*)dst = *(uint4*)v;
}

// ---------------- partition stage A: per-bucket totals ----------------------
__global__ __launch_bounds__(256) void bucket_hist_k(
    const int* __restrict__ dst, int E, int* __restrict__ gcnt, int nbuckets)
{
  __shared__ int cnt[512];
  const int tid = threadIdx.x;
  for (int b = tid; b < nbuckets; b += 256) cnt[b] = 0;
  __syncthreads();
  const int base = blockIdx.x * EPB;
  for (int j = tid; j < EPB; j += 256) {
    const int e = base + j;
    if (e < E) atomicAdd(&cnt[dst[e] >> BSH], 1);
  }
  __syncthreads();
  for (int b = tid; b < nbuckets; b += 256)
    if (cnt[b]) atomicAdd(&gcnt[b], cnt[b]);
}

// ---------------- partition stage B: scan buckets, init padded cursors ------
__global__ __launch_bounds__(512) void bucket_scan_k(
    const int* __restrict__ gcnt, int* __restrict__ boffs,
    int* __restrict__ pcur, int nbuckets, int E)
{
  __shared__ int s[512];
  const int t = threadIdx.x;
  const int x = (t < nbuckets) ? gcnt[t] : 0;
  s[t] = x; __syncthreads();
  for (int off = 1; off < 512; off <<= 1) {
    const int v = (t >= off) ? s[t - off] : 0;
    __syncthreads(); s[t] += v; __syncthreads();
  }
  if (t < nbuckets) {
    const int excl = s[t] - x;
    boffs[t] = excl;
    pcur[t * 16] = excl;          // 64B-padded cursor: own cache line
  }
  if (t == 0) boffs[nbuckets] = E;
}

// ---------------- partition stage C: block-aggregated bucket append ---------
__global__ __launch_bounds__(256) void pack2_k(
    const int* __restrict__ src, const int* __restrict__ dst,
    const int* __restrict__ et, int E,
    int* __restrict__ pcur, int* __restrict__ ep_log, int nbuckets)
{
  __shared__ int cnt[512];
  __shared__ int basel[512];
  __shared__ unsigned short ranks[EPB];
  const int tid = threadIdx.x;
  for (int b = tid; b < nbuckets; b += 256) cnt[b] = 0;
  __syncthreads();
  const int base = blockIdx.x * EPB;
  for (int j = tid; j < EPB; j += 256) {
    const int e = base + j;
    if (e < E) ranks[j] = (unsigned short)atomicAdd(&cnt[dst[e] >> BSH], 1);
  }
  __syncthreads();
  for (int b = tid; b < nbuckets; b += 256)
    basel[b] = cnt[b] ? atomicAdd(&pcur[b * 16], cnt[b]) : 0;
  __syncthreads();
  for (int j = tid; j < EPB; j += 256) {
    const int e = base + j;
    if (e < E) {
      const int d = dst[e];
      const int pos = basel[d >> BSH] + ranks[j];
      ep_log[pos] = ((d & 255) << 19) | (et[e] << 17) | src[e];
    }
  }
}

// ------- partition stage D: per-bucket counting sort -> ep + rowp -----------
__global__ __launch_bounds__(256) void bucket_sort2_k(
    const int* __restrict__ boffs, const int* __restrict__ ep_log,
    int* __restrict__ ep, int* __restrict__ rowp, int Nn, int E)
{
  __shared__ int ent[EPB];
  __shared__ int cntA[256];
  __shared__ int curA[256];
  const int b = blockIdx.x;
  const int tid = threadIdx.x;
  const int beg = boffs[b], end = boffs[b + 1];
  const int n = end - beg;
  const bool inl = (n <= EPB);
  if (inl) for (int i = tid; i < n; i += 256) ent[i] = ep_log[beg + i];
  cntA[tid] = 0;
  __syncthreads();
  for (int i = tid; i < n; i += 256) {
    const int v = inl ? ent[i] : ep_log[beg + i];
    atomicAdd(&cntA[v >> 19], 1);
  }
  __syncthreads();
  const int my = cntA[tid];
  for (int off = 1; off < 256; off <<= 1) {       // inclusive scan
    const int v = (tid >= off) ? cntA[tid - off] : 0;
    __syncthreads(); cntA[tid] += v; __syncthreads();
  }
  const int excl = cntA[tid] - my;
  const int node = (b << BSH) + tid;
  if (node < Nn) rowp[node] = beg + excl;
  if (b == 0 && tid == 0) rowp[Nn] = E;
  curA[tid] = excl;
  __syncthreads();
  for (int i = tid; i < n; i += 256) {
    const int v = inl ? ent[i] : ep_log[beg + i];
    const int p = atomicAdd(&curA[v >> 19], 1);
    ep[beg + p] = v & 0x7FFFF;                    // (et<<17)|src
  }
}

// ------------- fused MFMA GEMM, all col-groups per block --------------------
// BN==1: stage A from fp32 agg applying y = relu(s*x + t); stats is a
// NSHADOW-way shadow array (32 x 256 floats) that gets reduced here.
template<int KSTEPS, int BN>
__global__ __launch_bounds__(256) void mfma_gemm_t(
    const float* __restrict__ Af,             // [M][K] fp32
    const unsigned short* __restrict__ Bpre,
    const float* __restrict__ bias,
    const float* __restrict__ stats,          // shadow sums (BN==1)
    const float* __restrict__ gamma, const float* __restrict__ beta,
    unsigned short* __restrict__ tmp_all,     // [fpGroup][M][H] bf16
    float* __restrict__ agg,                  // [M][H] fp32 out
    int M, int nGroups, int fpGroup, float invN)
{
  constexpr int K = KSTEPS * 32;
  constexpr int strideL = K + 8;
  __shared__ unsigned short Alds[128 * strideL];
  __shared__ float sbt[128], tbt[128];
  const int tid = threadIdx.x;
  const int rowBase = blockIdx.x * 128;

  if (BN) {
    if (tid < 128) {
      float su = 0.f, qu = 0.f;
#pragma unroll
      for (int c = 0; c < NSHADOW; ++c) {
        su += stats[c * 256 + tid];
        qu += stats[c * 256 + 128 + tid];
      }
      const float mu  = su * invN;
      const float var = qu * invN - mu * mu;
      const float s = gamma[tid] * rsqrtf(var + 1e-5f);
      sbt[tid] = s; tbt[tid] = beta[tid] - s * mu;
    }
    __syncthreads();
  }

  constexpr int cpr4 = K / 4;                 // float4 chunks per row
  for (int c = tid; c < 128 * cpr4; c += 256) {
    const int row = c / cpr4;
    const int k4  = c % cpr4;
    const int grow = rowBase + row;
    float4 v = make_float4(0.f, 0.f, 0.f, 0.f);
    if (grow < M) v = *(const float4*)(Af + (size_t)grow * K + k4 * 4);
    unsigned short o[4];
    if (BN) {
      const int col = k4 * 4;
      o[0] = f2bf(fmaxf(fmaf(sbt[col+0], v.x, tbt[col+0]), 0.f));
      o[1] = f2bf(fmaxf(fmaf(sbt[col+1], v.y, tbt[col+1]), 0.f));
      o[2] = f2bf(fmaxf(fmaf(sbt[col+2], v.z, tbt[col+2]), 0.f));
      o[3] = f2bf(fmaxf(fmaf(sbt[col+3], v.w, tbt[col+3]), 0.f));
    } else {
      o[0] = f2bf(v.x); o[1] = f2bf(v.y); o[2] = f2bf(v.z); o[3] = f2bf(v.w);
    }
    *(uint2*)(Alds + (size_t)row * strideL + k4 * 4) = *(uint2*)o;
  }
  __syncthreads();

  const int wave = tid >> 6, lane = tid & 63;
  const int quad = lane >> 4, l15 = lane & 15;

  bf16x8 a[2][KSTEPS];
#pragma unroll
  for (int rt = 0; rt < 2; ++rt) {
    const int row = wave * 32 + rt * 16 + l15;
#pragma unroll
    for (int s = 0; s < KSTEPS; ++s)
      a[rt][s] = *(const bf16x8*)(Alds + (size_t)row * strideL + s * 32 + quad * 8);
  }

  for (int g = 0; g < nGroups; ++g) {
    f32x4 acc[2][8] = {};
    const unsigned short* bp = Bpre + ((size_t)g * 8) * KSTEPS * 64 * 8;
#pragma unroll
    for (int s = 0; s < KSTEPS; ++s) {
#pragma unroll
      for (int c = 0; c < 8; ++c) {
        const bf16x8 b = *(const bf16x8*)(bp + (size_t)((c * KSTEPS + s) * 64 + lane) * 8);
        acc[0][c] = __builtin_amdgcn_mfma_f32_16x16x32_bf16(a[0][s], b, acc[0][c], 0, 0, 0);
        acc[1][c] = __builtin_amdgcn_mfma_f32_16x16x32_bf16(a[1][s], b, acc[1][c], 0, 0, 0);
      }
    }
    if (g < fpGroup) {
      unsigned short* outp = tmp_all + (size_t)g * M * H;
#pragma unroll
      for (int rt = 0; rt < 2; ++rt)
#pragma unroll
        for (int reg = 0; reg < 4; ++reg) {
          const int row = rowBase + wave * 32 + rt * 16 + quad * 4 + reg;
          if (row >= M) continue;
#pragma unroll
          for (int c = 0; c < 8; ++c)
            outp[(size_t)row * H + c * 16 + l15] = f2bf(acc[rt][c][reg]);
        }
    } else {
#pragma unroll
      for (int rt = 0; rt < 2; ++rt)
#pragma unroll
        for (int reg = 0; reg < 4; ++reg) {
          const int row = rowBase + wave * 32 + rt * 16 + quad * 4 + reg;
          if (row >= M) continue;
#pragma unroll
          for (int c = 0; c < 8; ++c) {
            const int col = c * 16 + l15;
            agg[(size_t)row * H + col] = acc[rt][c][reg] + bias[col];
          }
        }
    }
  }
}

// ----- CSR gather (bf16 messages) + fused BN-stats into shadow copies -------
// One wave per node (grid-stride). Edge indices fetched lane-parallel and
// broadcast with shfl; row loads issued in unrolled chunks of 8 for MLP.
__global__ __launch_bounds__(256) void gather_csr_k(
    const unsigned short* __restrict__ tmp_all, const int* __restrict__ rowp,
    const int* __restrict__ ep, float* __restrict__ agg,
    float* __restrict__ shadow, int Nn)
{
  __shared__ float sAcc[4][128];
  __shared__ float qAcc[4][128];
  const int tid = threadIdx.x;
  const int wave = tid >> 6, lane = tid & 63;
  sAcc[wave][lane] = 0.f;  sAcc[wave][64 + lane] = 0.f;
  qAcc[wave][lane] = 0.f;  qAcc[wave][64 + lane] = 0.f;

  const int waveId = blockIdx.x * 4 + wave;
  const int nWaves = gridDim.x * 4;
  for (int node = waveId; node < Nn; node += nWaves) {
    const int beg = rowp[node];
    const int end = rowp[node + 1];
    float2 acc = ((const float2*)(agg + (size_t)node * H))[lane];
    int e = beg;
    int cnt = end - beg;
    while (cnt > 0) {
      const int take = cnt < 64 ? cnt : 64;
      const int pv = (lane < take) ? ep[e + lane] : 0;
      for (int j0 = 0; j0 < take; j0 += 8) {
        const int m = take - j0;
        int pj[8];
#pragma unroll
        for (int j = 0; j < 8; ++j) pj[j] = __shfl(pv, j0 + j);
        if (m >= 8) {
          unsigned vv[8];
#pragma unroll
          for (int j = 0; j < 8; ++j)
            vv[j] = *(const unsigned*)(tmp_all +
                ((size_t)(pj[j] >> 17) * Nn + (pj[j] & 0x1FFFF)) * H + lane * 2);
#pragma unroll
          for (int j = 0; j < 8; ++j) {
            acc.x += bf2f((unsigned short)(vv[j] & 0xFFFF));
            acc.y += bf2f((unsigned short)(vv[j] >> 16));
          }
        } else {
          for (int j = 0; j < m; ++j) {
            const unsigned v = *(const unsigned*)(tmp_all +
                ((size_t)(pj[j] >> 17) * Nn + (pj[j] & 0x1FFFF)) * H + lane * 2);
            acc.x += bf2f((unsigned short)(v & 0xFFFF));
            acc.y += bf2f((unsigned short)(v >> 16));
          }
        }
      }
      e += take; cnt -= take;
    }
    ((float2*)(agg + (size_t)node * H))[lane] = acc;
    sAcc[wave][lane * 2]     += acc.x;
    sAcc[wave][lane * 2 + 1] += acc.y;
    qAcc[wave][lane * 2]     += acc.x * acc.x;
    qAcc[wave][lane * 2 + 1] += acc.y * acc.y;
  }
  __syncthreads();
  float* sh = shadow + (size_t)(blockIdx.x & (NSHADOW - 1)) * 256;
  if (tid < 128) {
    atomicAdd(&sh[tid], sAcc[0][tid] + sAcc[1][tid] + sAcc[2][tid] + sAcc[3][tid]);
  } else {
    const int c = tid - 128;
    atomicAdd(&sh[128 + c], qAcc[0][c] + qAcc[1][c] + qAcc[2][c] + qAcc[3][c]);
  }
}

// ---------------------------- final BN helpers ------------------------------
__global__ __launch_bounds__(256) void bn_stats_k(
    const float* __restrict__ X, int Nn, float* __restrict__ stats)
{
  const int col  = threadIdx.x & 127;
  const int half = threadIdx.x >> 7;
  float s = 0.f, q = 0.f;
  for (int row = blockIdx.x * 2 + half; row < Nn; row += gridDim.x * 2) {
    const float v = X[(size_t)row * H + col];
    s += v; q += v * v;
  }
  __shared__ float ls[256], lq[256];
  ls[threadIdx.x] = s; lq[threadIdx.x] = q;
  __syncthreads();
  if (threadIdx.x < 128) {
    atomicAdd(&stats[col],     ls[threadIdx.x] + ls[threadIdx.x + 128]);
    atomicAdd(&stats[H + col], lq[threadIdx.x] + lq[threadIdx.x + 128]);
  }
}

__global__ __launch_bounds__(256) void bn_apply_k(
    const float* __restrict__ X, const float* __restrict__ stats,
    const float* __restrict__ gamma, const float* __restrict__ beta,
    float* __restrict__ out_f, int Nn)
{
  const size_t i = (size_t)blockIdx.x * 256 + threadIdx.x;
  const size_t total = (size_t)Nn * H;
  if (i >= total) return;
  const int col = (int)(i & 127);
  const float mu  = stats[col] / Nn;
  const float var = stats[H + col] / Nn - mu * mu;
  const float inv = rsqrtf(var + 1e-5f);
  out_f[i] = fmaf(gamma[col] * inv, X[i] - mu, beta[col]);
}

// ---------------------------------------------------------------------------
extern "C" void kernel_launch(void* const* d_in, const int* in_sizes, int n_in,
                              void* d_out, int out_size, void* d_ws, size_t ws_size,
                              hipStream_t stream)
{
  const float* x     = (const float*)d_in[0];
  const int*   src   = (const int*)d_in[1];
  const int*   dst   = (const int*)d_in[2];
  const int*   et    = (const int*)d_in[3];
  const float* W0    = (const float*)d_in[4];
  const float* loop0 = (const float*)d_in[5];
  const float* b0    = (const float*)d_in[6];
  const float* g0    = (const float*)d_in[7];
  const float* be0   = (const float*)d_in[8];
  const float* Ws    = (const float*)d_in[9];
  const float* loops = (const float*)d_in[10];
  const float* bs    = (const float*)d_in[11];
  const float* gs    = (const float*)d_in[12];
  const float* bes   = (const float*)d_in[13];
  const float* Wl    = (const float*)d_in[14];
  const float* bl    = (const float*)d_in[15];
  const float* gl    = (const float*)d_in[16];
  const float* bel   = (const float*)d_in[17];

  const int E = in_sizes[1];
  const int F_in = 64;
  const int N = in_sizes[0] / F_in;
  const int R = in_sizes[4] / (F_in * H);
  const int L = in_sizes[9] / (R * H * H);
  const float invN = 1.0f / (float)N;

  float* outp = (float*)d_out;

  // ---- workspace layout ----
  char* p = (char*)d_ws;
  auto alloc = [&](size_t bytes) { char* r = p; p += (bytes + 255) & ~size_t(255); return r; };
  const int nbuckets = (N + (1 << BSH) - 1) >> BSH;       // <= 512 (N<=131072)
  const int c0 = (R + 1) * 8 * (F_in / 32) * 64;
  const int ch = (R + 1) * 8 * (H / 32) * 64;
  const int cf = 8 * (H / 32) * 64;
  const int shadowN = NSHADOW * 256;                      // floats per layer
  float*          agg      = (float*)alloc((size_t)N * H * 4);
  float*          shadow   = (float*)alloc((size_t)(L + 1) * shadowN * 4);
  float*          statsF   = (float*)alloc(2 * H * 4);    // final BN (plain)
  unsigned short* tmp_all  = (unsigned short*)alloc((size_t)R * N * H * 2);
  unsigned short* Bpre_all = (unsigned short*)alloc((size_t)(c0 + L * ch + cf) * 8 * 2);
  int*            gcnt     = (int*)alloc((size_t)nbuckets * 4);
  int*            boffs    = (int*)alloc((size_t)(nbuckets + 1) * 4);
  int*            pcur     = (int*)alloc((size_t)nbuckets * 16 * 4);   // 64B padded
  int*            rowp     = (int*)alloc((size_t)(N + 1) * 4);
  int*            ep       = (int*)alloc((size_t)E * 4);
  int*            ep_log   = (int*)alloc((size_t)E * 4);
  (void)ws_size;

  const int pblocks = (E + EPB - 1) / EPB;
  const int rowBlocks = (N + 127) / 128;

  // ---- prepack all weights (bf16 B-fragment layout) ----
  hipLaunchKernelGGL(prep_w_k, dim3((c0 + 255) / 256), dim3(256), 0, stream,
                     W0, loop0, Bpre_all, F_in, (R + 1) * 8, R);
  for (int l = 0; l < L; ++l)
    hipLaunchKernelGGL(prep_w_k, dim3((ch + 255) / 256), dim3(256), 0, stream,
                       Ws + (size_t)l * R * H * H, loops + (size_t)l * H * H,
                       Bpre_all + (size_t)(c0 + l * ch) * 8, H, (R + 1) * 8, R);
  hipLaunchKernelGGL(prep_w_k, dim3((cf + 255) / 256), dim3(256), 0, stream,
                     (const float*)nullptr, Wl, Bpre_all + (size_t)(c0 + L * ch) * 8, H, 8, 0);

  // ---- zero shadow stats + final stats + bucket counters ----
  {
    const int nz = (L + 1) * shadowN + 2 * H;
    hipLaunchKernelGGL(zero_k, dim3((nz + 255) / 256), dim3(256), 0, stream, shadow, nz);
  }
  hipLaunchKernelGGL(zero_k, dim3((nbuckets + 255) / 256), dim3(256), 0, stream,
                     (float*)gcnt, nbuckets);

  // ---- partition: hist -> scan -> pack -> per-bucket sort ----
  hipLaunchKernelGGL(bucket_hist_k, dim3(pblocks), dim3(256), 0, stream, dst, E, gcnt, nbuckets);
  hipLaunchKernelGGL(bucket_scan_k, dim3(1), dim3(512), 0, stream, gcnt, boffs, pcur, nbuckets, E);
  hipLaunchKernelGGL(pack2_k, dim3(pblocks), dim3(256), 0, stream,
                     src, dst, et, E, pcur, ep_log, nbuckets);
  hipLaunchKernelGGL(bucket_sort2_k, dim3(nbuckets), dim3(256), 0, stream,
                     boffs, ep_log, ep, rowp, N, E);

  // ---- layer 0: GEMM from x (no BN), gather w/ fused shadow stats ----
  hipLaunchKernelGGL((mfma_gemm_t<2, 0>), dim3(rowBlocks), dim3(256), 0, stream,
                     x, Bpre_all, b0, (const float*)nullptr,
                     (const float*)nullptr, (const float*)nullptr,
                     tmp_all, agg, N, R + 1, R, invN);
  hipLaunchKernelGGL(gather_csr_k, dim3(2048), dim3(256), 0, stream,
                     tmp_all, rowp, ep, agg, shadow, N);

  // ---- hidden conv layers: BN(prev) fused into GEMM A-staging ----
  for (int l = 0; l < L; ++l) {
    const float* gam = (l == 0) ? g0 : gs + (size_t)(l - 1) * H;
    const float* bet = (l == 0) ? be0 : bes + (size_t)(l - 1) * H;
    hipLaunchKernelGGL((mfma_gemm_t<4, 1>), dim3(rowBlocks), dim3(256), 0, stream,
                       agg, Bpre_all + (size_t)(c0 + l * ch) * 8, bs + (size_t)l * H,
                       shadow + (size_t)l * shadowN, gam, bet,
                       tmp_all, agg, N, R + 1, R, invN);
    hipLaunchKernelGGL(gather_csr_k, dim3(2048), dim3(256), 0, stream,
                       tmp_all, rowp, ep, agg, shadow + (size_t)(l + 1) * shadowN, N);
  }

  // ---- final linear (BN(last conv) fused) + final BN -> d_out ----
  {
    const float* gam = (L == 0) ? g0 : gs + (size_t)(L - 1) * H;
    const float* bet = (L == 0) ? be0 : bes + (size_t)(L - 1) * H;
    hipLaunchKernelGGL((mfma_gemm_t<4, 1>), dim3(rowBlocks), dim3(256), 0, stream,
                       agg, Bpre_all + (size_t)(c0 + L * ch) * 8, bl,
                       shadow + (size_t)L * shadowN, gam, bet,
                       (unsigned short*)nullptr, agg, N, 1, 0, invN);
    hipLaunchKernelGGL(bn_stats_k, dim3(512), dim3(256), 0, stream, agg, N, statsF);
    const int apply_blocks = (int)(((size_t)N * H + 255) / 256);
    hipLaunchKernelGGL(bn_apply_k, dim3(apply_blocks), dim3(256), 0, stream,
                       agg, statsF, gl, bel, outp, N);
  }
}